// Round 9
// baseline (532.038 us; speedup 1.0000x reference)
//
#include <hip/hip_runtime.h>

#define N_NODES 50000
#define N_EDGES 800000
#define F_IN 24
#define HDIM 128
#define N_GRAPHS 100
#define BN_EPS 1e-5f
#define NBLK 196                          // ceil(N_NODES/256)
#define ROWS_PER_GRAPH (N_NODES / N_GRAPHS)
#define MM_GRID 782                       // ceil(N_NODES/64), 64-row tiles
#define HIST_BLKS ((N_EDGES + 255) / 256) // 3125
#define PREP_BLKS (F_IN + 2 * HDIM)       // 280
#define SSTR 32                           // 32 floats = 128 B: one cache line per channel
#define SUMS_PER_LAYER (256 * SSTR)       // 8192 floats = 32 KB
#define STATS_TILES 392                   // 128 rows/tile
#define POOL_CHUNKS 10
#define POOL_BLKS (N_GRAPHS * POOL_CHUNKS)          // 1000 blocks
#define ROWS_PER_CHUNK (ROWS_PER_GRAPH / POOL_CHUNKS) // 50

// LESSON (R2): do NOT fuse BN stats into k_agg via per-block atomics (3.2M+ atomics).
// LESSON (R1): no nontemporal hints (A/h are LLC-reused by next dispatch).
// LESSON (R4/R5/R8): agg is at its compulsory-traffic floor (~92MB = 8 XCDs x
// unique-rows x 256B at LLC random BW). Latency fixes, L2 blocking, and
// issue-rate halving (h4) were ALL neutral. Stop optimizing agg internals.
// LESSON (R7): block-role fusion needs compatible resource footprints (scatter
// inherited mm1's 208 VGPR -> occupancy collapse). This round's merges keep
// footprints matched, and use ticket-STEALING (any resident block can execute
// any stage-tile) -> deadlock-free under undefined dispatch order.
// R9 (this): dispatch count 14 -> 10. Cross-block data INSIDE a kernel travels
// only via device atomics (atomicExch publish / atomicAdd(p,0) poll — k_scanall-
// proven pattern); __syncthreads() drains vmcnt before each done-signal.

typedef _Float16 h2 __attribute__((ext_vector_type(2)));
typedef _Float16 h4 __attribute__((ext_vector_type(4)));
typedef _Float16 f16x8 __attribute__((ext_vector_type(8)));
typedef float f32x4 __attribute__((ext_vector_type(4)));

__device__ inline h4 max4(h4 a, h4 b) { return __builtin_elementwise_max(a, b); }
__device__ inline h4 shfl_xor_h4(h4 v, int m) {
    union { h4 h; int2 i; } u;
    u.h = v;
    u.i.x = __shfl_xor(u.i.x, m);
    u.i.y = __shfl_xor(u.i.y, m);
    return u.h;
}

// ---------------- layer-1 matmul (vector, K=24), BOTH planes in one block --------
template <int K, int KC>
__global__ __launch_bounds__(256) void k_mm1(const float* __restrict__ X,
                                             const float* __restrict__ Wcat,
                                             const float* __restrict__ bias,
                                             _Float16* __restrict__ A, _Float16* __restrict__ C) {
    __shared__ float Xs[KC * 68];
    __shared__ float Ws[KC * 256];
    int tid = threadIdx.x;
    int row0 = blockIdx.x * 64;
    int cg = tid & 31;
    int rg = tid >> 5;

    float accA[8][4], accC[8][4];
#pragma unroll
    for (int ri = 0; ri < 8; ++ri)
#pragma unroll
        for (int ci = 0; ci < 4; ++ci) {
            accA[ri][ci] = bias[cg * 4 + ci];
            accC[ri][ci] = 0.f;
        }

    for (int k0 = 0; k0 < K; k0 += KC) {
        __syncthreads();
        {
            const int C4 = KC / 4;
            for (int i = tid; i < 64 * C4; i += 256) {
                int c4 = i % C4, r = i / C4;
                int row = row0 + r;
                float4 v = make_float4(0.f, 0.f, 0.f, 0.f);
                if (row < N_NODES) v = *(const float4*)&X[row * K + k0 + c4 * 4];
                Xs[(c4 * 4 + 0) * 68 + r] = v.x;
                Xs[(c4 * 4 + 1) * 68 + r] = v.y;
                Xs[(c4 * 4 + 2) * 68 + r] = v.z;
                Xs[(c4 * 4 + 3) * 68 + r] = v.w;
            }
        }
        for (int i = tid; i < KC * 64; i += 256) {
            int c4 = i & 63, kr = i >> 6;
            *(float4*)&Ws[kr * 256 + c4 * 4] =
                *(const float4*)&Wcat[(k0 + kr) * 256 + c4 * 4];
        }
        __syncthreads();
#pragma unroll
        for (int kk = 0; kk < KC; ++kk) {
            float4 t0 = *(const float4*)&Xs[kk * 68 + rg * 8];
            float4 t1 = *(const float4*)&Xs[kk * 68 + rg * 8 + 4];
            float4 wa = *(const float4*)&Ws[kk * 256 + cg * 4];
            float4 wc = *(const float4*)&Ws[kk * 256 + 128 + cg * 4];
            float t[8] = {t0.x, t0.y, t0.z, t0.w, t1.x, t1.y, t1.z, t1.w};
            float wav[4] = {wa.x, wa.y, wa.z, wa.w};
            float wcv[4] = {wc.x, wc.y, wc.z, wc.w};
#pragma unroll
            for (int ri = 0; ri < 8; ++ri)
#pragma unroll
                for (int ci = 0; ci < 4; ++ci) {
                    accA[ri][ci] += t[ri] * wav[ci];
                    accC[ri][ci] += t[ri] * wcv[ci];
                }
        }
    }

#pragma unroll
    for (int ri = 0; ri < 8; ++ri) {
        int row = row0 + rg * 8 + ri;
        if (row < N_NODES) {
            union { h2 h[2]; uint2 u; } pa;
            pa.h[0] = h2{(_Float16)accA[ri][0], (_Float16)accA[ri][1]};
            pa.h[1] = h2{(_Float16)accA[ri][2], (_Float16)accA[ri][3]};
            *(uint2*)&A[row * HDIM + cg * 4] = pa.u;
            union { h2 h[2]; uint2 u; } pk;
            pk.h[0] = h2{(_Float16)accC[ri][0], (_Float16)accC[ri][1]};
            pk.h[1] = h2{(_Float16)accC[ri][2], (_Float16)accC[ri][3]};
            *(uint2*)&C[row * HDIM + cg * 4] = pk.u;
        }
    }
}

// ---------------- layers 2/3: stats(steal) + MFMA matmul in ONE dispatch ---------
// Phase 1: blocks steal 392 stats tiles (LDS scratch overlaid on Wh — no extra
// LDS, occupancy unchanged), atomicAdd into sums, signal done (after syncthreads
// drains vmcnt). Phase 2: poll done==392, then plain-read sums (atomic results
// live at LLC; this XCD's L2 never cached those lines this kernel) and run the
// 2-plane MFMA matmul as before.
__global__ __launch_bounds__(256) void k_mmf(const _Float16* __restrict__ X,
                                             const _Float16* __restrict__ Wf,
                                             const float* __restrict__ bias,
                                             float* __restrict__ sums,
                                             const float* __restrict__ g,
                                             const float* __restrict__ be,
                                             _Float16* __restrict__ A, _Float16* __restrict__ C,
                                             unsigned* __restrict__ ticket,
                                             unsigned* __restrict__ done) {
    __shared__ _Float16 Xh[16 * 520];
    __shared__ __attribute__((aligned(16))) _Float16 Wh[128 * 128];
    __shared__ float scs[128], shs[128];
    __shared__ int tkt;
    int tid = threadIdx.x;
    int lane = tid & 63, wv = tid >> 6;
    int row0 = blockIdx.x * 64;

    // ---- phase 1: steal stats tiles ----
    {
        float4* ls  = (float4*)Wh;           // 4KB scratch inside Wh (unstaged yet)
        float4* ls2 = ls + 256;              // +4KB
        for (;;) {
            if (tid == 0) tkt = (int)atomicAdd(ticket, 1u);
            __syncthreads();
            int b = tkt;
            if (b >= STATS_TILES) break;
            int c4 = tid & 31, rg = tid >> 5;
            int r0 = b * 128;
            float4 s = make_float4(0.f, 0.f, 0.f, 0.f);
            float4 s2 = make_float4(0.f, 0.f, 0.f, 0.f);
#pragma unroll 4
            for (int it = 0; it < 16; ++it) {
                int row = r0 + rg * 16 + it;
                if (row < N_NODES) {
                    h4 hv = *(const h4*)&X[row * HDIM + c4 * 4];
                    float4 v = make_float4((float)hv.x, (float)hv.y, (float)hv.z, (float)hv.w);
                    s.x += v.x; s.y += v.y; s.z += v.z; s.w += v.w;
                    s2.x += v.x * v.x; s2.y += v.y * v.y; s2.z += v.z * v.z; s2.w += v.w * v.w;
                }
            }
            ls[tid] = s; ls2[tid] = s2;
            __syncthreads();
            if (tid < 32) {
                float4 a = ls[tid], a2 = ls2[tid];
#pragma unroll
                for (int j = 1; j < 8; ++j) {
                    float4 bb = ls[j * 32 + tid], b2 = ls2[j * 32 + tid];
                    a.x += bb.x; a.y += bb.y; a.z += bb.z; a.w += bb.w;
                    a2.x += b2.x; a2.y += b2.y; a2.z += b2.z; a2.w += b2.w;
                }
                int c = tid * 4;
                atomicAdd(&sums[(c + 0) * SSTR], a.x);
                atomicAdd(&sums[(c + 1) * SSTR], a.y);
                atomicAdd(&sums[(c + 2) * SSTR], a.z);
                atomicAdd(&sums[(c + 3) * SSTR], a.w);
                atomicAdd(&sums[(128 + c + 0) * SSTR], a2.x);
                atomicAdd(&sums[(128 + c + 1) * SSTR], a2.y);
                atomicAdd(&sums[(128 + c + 2) * SSTR], a2.z);
                atomicAdd(&sums[(128 + c + 3) * SSTR], a2.w);
            }
            __syncthreads();                 // drains vmcnt: atomics completed
            if (tid == 0) atomicAdd(done, 1u);
            __syncthreads();                 // before reusing ls/ls2
        }
        if (tid == 0) { while (atomicAdd(done, 0u) < STATS_TILES) {} }
        __syncthreads();
    }

    // ---- phase 2: the matmul (unchanged math) ----
    if (tid < 128) {
        float S  = sums[tid * SSTR];
        float S2 = sums[(128 + tid) * SSTR];
        float mean = S / (float)N_NODES;
        float var = fmaxf(S2 / (float)N_NODES - mean * mean, 0.f);
        float scv = g[tid] / sqrtf(var + BN_EPS);
        scs[tid] = scv;
        shs[tid] = be[tid] - mean * scv;
    }
    {
        const uint4* s = (const uint4*)Wf;          // plane 0
        uint4* d = (uint4*)Wh;
        for (int i = tid; i < 2048; i += 256) d[i] = s[i];
    }
    __syncthreads();
    for (int i = tid; i < 64 * 32; i += 256) {
        int k4 = i & 31, rl = i >> 5;
        int row = row0 + rl;
        float4 v = make_float4(0.f, 0.f, 0.f, 0.f);
        if (row < N_NODES) {
            h4 xv = *(const h4*)&X[row * HDIM + k4 * 4];
            v = make_float4((float)xv.x, (float)xv.y, (float)xv.z, (float)xv.w);
        }
        int c = k4 * 4;
        v.x = fmaxf(v.x * scs[c + 0] + shs[c + 0], 0.f);
        v.y = fmaxf(v.y * scs[c + 1] + shs[c + 1], 0.f);
        v.z = fmaxf(v.z * scs[c + 2] + shs[c + 2], 0.f);
        v.w = fmaxf(v.w * scs[c + 3] + shs[c + 3], 0.f);
        int rt = rl >> 4, m = rl & 15, kc = k4 >> 3, q = (k4 >> 1) & 3, jh = k4 & 1;
        _Float16* dp = Xh + (rt * 4 + kc) * 520 + (q * 16 + m) * 8 + jh * 4;
        dp[0] = (_Float16)v.x; dp[1] = (_Float16)v.y;
        dp[2] = (_Float16)v.z; dp[3] = (_Float16)v.w;
    }
    __syncthreads();

    int n = lane & 15, q = lane >> 4;
    f32x4 acc[8];

#pragma unroll
    for (int nt = 0; nt < 8; ++nt) {
        float b0 = bias[nt * 16 + n];
        acc[nt] = f32x4{b0, b0, b0, b0};
    }
#pragma unroll
    for (int kc = 0; kc < 4; ++kc) {
        f16x8 a = *(const f16x8*)(Xh + (wv * 4 + kc) * 520 + lane * 8);
#pragma unroll
        for (int nt = 0; nt < 8; ++nt) {
            f16x8 b = *(const f16x8*)(Wh + ((nt * 4 + kc) * 64 + lane) * 8);
            acc[nt] = __builtin_amdgcn_mfma_f32_16x16x32_f16(a, b, acc[nt], 0, 0, 0);
        }
    }
#pragma unroll
    for (int nt = 0; nt < 8; ++nt) {
#pragma unroll
        for (int r = 0; r < 4; ++r) {
            int row = row0 + wv * 16 + q * 4 + r;
            if (row < N_NODES) A[row * HDIM + nt * 16 + n] = (_Float16)acc[nt][r];
        }
    }
    __syncthreads();
    {
        const uint4* s = (const uint4*)(Wf + 16384);   // plane 1
        uint4* d = (uint4*)Wh;
        for (int i = tid; i < 2048; i += 256) d[i] = s[i];
    }
    __syncthreads();

#pragma unroll
    for (int nt = 0; nt < 8; ++nt) acc[nt] = f32x4{0.f, 0.f, 0.f, 0.f};
#pragma unroll
    for (int kc = 0; kc < 4; ++kc) {
        f16x8 a = *(const f16x8*)(Xh + (wv * 4 + kc) * 520 + lane * 8);
#pragma unroll
        for (int nt = 0; nt < 8; ++nt) {
            f16x8 b = *(const f16x8*)(Wh + ((nt * 4 + kc) * 64 + lane) * 8);
            acc[nt] = __builtin_amdgcn_mfma_f32_16x16x32_f16(a, b, acc[nt], 0, 0, 0);
        }
    }
#pragma unroll
    for (int nt = 0; nt < 8; ++nt) {
#pragma unroll
        for (int r = 0; r < 4; ++r) {
            int row = row0 + wv * 16 + q * 4 + r;
            if (row < N_NODES) C[row * HDIM + nt * 16 + n] = (_Float16)acc[nt][r];
        }
    }
}

// ---------------- fused: weight prep + degree histogram (rank recorded) ----------
__global__ void k_pre(const float* __restrict__ W1, const float* __restrict__ W2,
                      const float* __restrict__ W3, float* __restrict__ Wcat1,
                      _Float16* __restrict__ Wf2, _Float16* __restrict__ Wf3,
                      const int* __restrict__ dst, unsigned* __restrict__ deg,
                      unsigned* __restrict__ rank) {
    int b = blockIdx.x;
    int j = threadIdx.x;
    if (b < F_IN) {
        float wb = W1[(b + F_IN) * HDIM + (j & 127)];
        float wt = W1[b * HDIM + (j & 127)];
        Wcat1[b * 256 + j] = (j < HDIM) ? (wt - wb) : wb;
    } else if (b < PREP_BLKS) {
        int idx = b - F_IN;
        int layer = idx >> 7;
        int k = idx & 127;
        const float* W = layer ? W3 : W2;
        _Float16* Wf   = layer ? Wf3 : Wf2;
        int col = j & 127;
        float wt = W[k * HDIM + col];
        float wb = W[(k + HDIM) * HDIM + col];
        float v = (j < 128) ? (wt - wb) : wb;
        int plane = j >> 7;
        int nt = col >> 4, n = col & 15, kc = k >> 5, q = (k >> 3) & 3, jj = k & 7;
        int f = ((nt * 4 + kc) * 4 + q) * 128 + n * 8 + jj;
        Wf[plane * 16384 + f] = (_Float16)v;
    } else {
        int e = (b - PREP_BLKS) * 256 + j;
        if (e < N_EDGES) rank[e] = atomicAdd(&deg[dst[e]], 1u);
    }
}

// ---------------- scan (stolen tiles) + scatter in ONE dispatch ------------------
// Blocks steal the 196 scan tiles via ticket (any resident blocks execute them —
// deadlock-free under undefined dispatch order; needs >=196 resident, guaranteed
// at this thin footprint). off published via atomicExch (LLC-coherent); scatter
// plain-reads off after the done-poll (reader L2 never cached off this kernel).
__global__ __launch_bounds__(256) void k_scansc(const unsigned* __restrict__ deg,
                                                unsigned* __restrict__ bsum,  // zeroed
                                                unsigned* __restrict__ off,
                                                const int* __restrict__ src,
                                                const int* __restrict__ dst,
                                                const unsigned* __restrict__ rank,
                                                unsigned* __restrict__ ssrc,
                                                unsigned* __restrict__ ticket,
                                                unsigned* __restrict__ done) {
    __shared__ unsigned s[256];
    __shared__ int tkt;
    int t = threadIdx.x;
    for (;;) {
        if (t == 0) tkt = (int)atomicAdd(ticket, 1u);
        __syncthreads();
        int b = tkt;
        if (b >= NBLK) break;
        int i = b * 256 + t;
        unsigned v = (i < N_NODES) ? deg[i] : 0u;
        s[t] = v;
        __syncthreads();
        for (int d = 1; d < 256; d <<= 1) {
            unsigned u = (t >= d) ? s[t - d] : 0u;
            __syncthreads();
            s[t] += u;
            __syncthreads();
        }
        unsigned locex = s[t] - v;
        if (t == 255) atomicExch(&bsum[b], s[255] + 1u);
        __syncthreads();
        unsigned bs = 0;
        if (t < NBLK) {
            unsigned x;
            do { x = atomicAdd(&bsum[t], 0u); } while (x == 0u);
            bs = x - 1u;
        }
        s[t] = (t < NBLK) ? bs : 0u;
        __syncthreads();
        for (int d = 1; d < 256; d <<= 1) {
            unsigned u = (t >= d) ? s[t - d] : 0u;
            __syncthreads();
            s[t] += u;
            __syncthreads();
        }
        unsigned bexcl = (b == 0) ? 0u : s[b - 1];
        if (i < N_NODES) atomicExch(&off[i], bexcl + locex);   // coherent publish
        __syncthreads();                  // drains vmcnt: off writes completed
        if (t == 0) atomicAdd(done, 1u);
        __syncthreads();                  // before reusing s[]
    }
    if (t == 0) { while (atomicAdd(done, 0u) < NBLK) {} }
    __syncthreads();
    int e = blockIdx.x * 256 + t;
    if (e < N_EDGES)
        ssrc[off[dst[e]] + rank[e]] = (unsigned)src[e];
}

// ---------------- aggregation: 2-rows-per-instruction gather (at fabric floor) ---
__global__ __launch_bounds__(256) void k_agg(const h4* __restrict__ A,
                                             const h4* __restrict__ Cc,
                                             const unsigned* __restrict__ off,
                                             const unsigned* __restrict__ deg,
                                             const unsigned* __restrict__ ssrc,
                                             h4* __restrict__ H) {
    __shared__ unsigned sl[4][64];
    int w = threadIdx.x >> 6;
    int lane = threadIdx.x & 63;
    int i = blockIdx.x * 4 + w;
    int d = (int)deg[i];
    unsigned o = off[i];
    int half = lane >> 5;
    int cl = lane & 31;
    h4 a = A[i * 32 + cl];
    union { unsigned short us[4]; h4 v; } nif;
    nif.us[0] = 0xFC00; nif.us[1] = 0xFC00; nif.us[2] = 0xFC00; nif.us[3] = 0xFC00;
    const h4 NI = nif.v;
    h4 m = NI;
    for (int base = 0; base < d; base += 64) {
        int cnt = min(64, d - base);
        if (lane < cnt) sl[w][lane] = ssrc[o + base + lane];
        int e = 0;
        for (; e + 16 <= cnt; e += 16) {
            unsigned s[8];
#pragma unroll
            for (int j = 0; j < 8; ++j) s[j] = sl[w][e + 2 * j + half];
            h4 v[8];
#pragma unroll
            for (int j = 0; j < 8; ++j) v[j] = Cc[s[j] * 32 + cl];
#pragma unroll
            for (int st = 4; st > 0; st >>= 1)
#pragma unroll
                for (int j = 0; j < st; ++j) v[j] = max4(v[j], v[j + st]);
            m = max4(m, v[0]);
        }
        if (e < cnt) {
            int last = cnt - 1;
            unsigned s[8];
#pragma unroll
            for (int j = 0; j < 8; ++j) {
                int idx = e + 2 * j + half;
                s[j] = sl[w][idx < last ? idx : last];
            }
            h4 v[8];
#pragma unroll
            for (int j = 0; j < 8; ++j) v[j] = Cc[s[j] * 32 + cl];
#pragma unroll
            for (int j = 0; j < 8; ++j) {
                int idx = e + 2 * j + half;
                if (idx >= cnt) v[j] = NI;
            }
#pragma unroll
            for (int st = 4; st > 0; st >>= 1)
#pragma unroll
                for (int j = 0; j < st; ++j) v[j] = max4(v[j], v[j + st]);
            m = max4(m, v[0]);
        }
    }
    m = max4(m, shfl_xor_h4(m, 32));
    if (lane < 32) {
        float h0 = (d > 0) ? fmaxf((float)a.x + (float)m.x, 0.f) : 0.f;
        float h1 = (d > 0) ? fmaxf((float)a.y + (float)m.y, 0.f) : 0.f;
        float h2v = (d > 0) ? fmaxf((float)a.z + (float)m.z, 0.f) : 0.f;
        float h3 = (d > 0) ? fmaxf((float)a.w + (float)m.w, 0.f) : 0.f;
        H[i * 32 + cl] = h4{(_Float16)h0, (_Float16)h1, (_Float16)h2v, (_Float16)h3};
    }
}

// ---------------- pooling + BN3 stats + final output in ONE dispatch -------------
// Each block does its pool tile: Pp via atomicExch (coherent), sums2 via atomicAdd,
// signal done after syncthreads-drain. Blocks 0..99 then poll done==1000 and run
// the per-graph BN3+linear+relu output (plain reads of Pp/sums2: atomic results
// at LLC, reader L2 clean for those lines).
__global__ __launch_bounds__(256) void k_poolout(const _Float16* __restrict__ H,
                                                 float* __restrict__ Pp,
                                                 float* __restrict__ sums,
                                                 const float* __restrict__ g3,
                                                 const float* __restrict__ be3,
                                                 const float* __restrict__ Wl,
                                                 const float* __restrict__ bl,
                                                 float* __restrict__ out,
                                                 unsigned* __restrict__ done) {
    __shared__ float4 ls[256], ls2[256];
    __shared__ float red[2];
    int t = threadIdx.x;
    int c4 = t & 31, rg = t >> 5;
    int b = blockIdx.x;
    int base = (b / POOL_CHUNKS) * ROWS_PER_GRAPH + (b % POOL_CHUNKS) * ROWS_PER_CHUNK;
    float4 s = make_float4(0.f, 0.f, 0.f, 0.f);
    float4 s2 = make_float4(0.f, 0.f, 0.f, 0.f);
#pragma unroll
    for (int j = 0; j < 7; ++j) {
        int rl = rg + j * 8;
        if (rl < ROWS_PER_CHUNK) {
            int row = base + rl;
            h4 hv = *(const h4*)&H[row * HDIM + c4 * 4];
            float4 v = make_float4((float)hv.x, (float)hv.y, (float)hv.z, (float)hv.w);
            s.x += v.x; s.y += v.y; s.z += v.z; s.w += v.w;
            s2.x += v.x * v.x; s2.y += v.y * v.y; s2.z += v.z * v.z; s2.w += v.w * v.w;
        }
    }
    ls[t] = s; ls2[t] = s2;
    __syncthreads();
    if (t < 32) {
        float4 a = ls[t], a2 = ls2[t];
#pragma unroll
        for (int j = 1; j < 8; ++j) {
            float4 q = ls[j * 32 + t], q2 = ls2[j * 32 + t];
            a.x += q.x; a.y += q.y; a.z += q.z; a.w += q.w;
            a2.x += q2.x; a2.y += q2.y; a2.z += q2.z; a2.w += q2.w;
        }
        int c = t * 4;
        atomicExch((unsigned*)&Pp[b * HDIM + c + 0], __float_as_uint(a.x));
        atomicExch((unsigned*)&Pp[b * HDIM + c + 1], __float_as_uint(a.y));
        atomicExch((unsigned*)&Pp[b * HDIM + c + 2], __float_as_uint(a.z));
        atomicExch((unsigned*)&Pp[b * HDIM + c + 3], __float_as_uint(a.w));
        atomicAdd(&sums[(c + 0) * SSTR], a.x);
        atomicAdd(&sums[(c + 1) * SSTR], a.y);
        atomicAdd(&sums[(c + 2) * SSTR], a.z);
        atomicAdd(&sums[(c + 3) * SSTR], a.w);
        atomicAdd(&sums[(128 + c + 0) * SSTR], a2.x);
        atomicAdd(&sums[(128 + c + 1) * SSTR], a2.y);
        atomicAdd(&sums[(128 + c + 2) * SSTR], a2.z);
        atomicAdd(&sums[(128 + c + 3) * SSTR], a2.w);
    }
    __syncthreads();                      // drains vmcnt: atomics completed
    if (t == 0) atomicAdd(done, 1u);

    if (b >= N_GRAPHS) return;            // only blocks 0..99 carry an out role
    if (t == 0) { while (atomicAdd(done, 0u) < POOL_BLKS) {} }
    __syncthreads();

    int gidx = b;
    float p = 0.f;
    if (t < 128) {
        float S  = sums[t * SSTR];
        float S2 = sums[(128 + t) * SSTR];
        float mean = S / (float)N_NODES;
        float var = fmaxf(S2 / (float)N_NODES - mean * mean, 0.f);
        float scv = g3[t] / sqrtf(var + BN_EPS);
        float shv = be3[t] - mean * scv;
        float pooled = 0.f;
#pragma unroll
        for (int j = 0; j < POOL_CHUNKS; ++j)
            pooled += Pp[(gidx * POOL_CHUNKS + j) * HDIM + t];
        p = (scv * (pooled * (1.f / (float)ROWS_PER_GRAPH)) + shv) * Wl[t];
    }
    for (int o = 32; o > 0; o >>= 1) p += __shfl_down(p, o);
    if (t < 128 && (t & 63) == 0) red[t >> 6] = p;
    __syncthreads();
    if (t == 0) out[gidx] = fmaxf(red[0] + red[1] + bl[0], 0.f);
}

// ---------------- launcher --------------------------------------------------------
extern "C" void kernel_launch(void* const* d_in, const int* in_sizes, int n_in,
                              void* d_out, int out_size, void* d_ws, size_t ws_size,
                              hipStream_t stream) {
    const float* x   = (const float*)d_in[0];
    const int* ei    = (const int*)d_in[1];
    const float* W1  = (const float*)d_in[3];
    const float* b1  = (const float*)d_in[4];
    const float* W2  = (const float*)d_in[5];
    const float* b2  = (const float*)d_in[6];
    const float* W3  = (const float*)d_in[7];
    const float* b3  = (const float*)d_in[8];
    const float* g1  = (const float*)d_in[9];
    const float* be1 = (const float*)d_in[10];
    const float* g2  = (const float*)d_in[11];
    const float* be2 = (const float*)d_in[12];
    const float* g3  = (const float*)d_in[13];
    const float* be3 = (const float*)d_in[14];
    const float* Wl  = (const float*)d_in[15];
    const float* bl  = (const float*)d_in[16];
    float* out = (float*)d_out;

    const int* srcp = ei;
    const int* dstp = ei + N_EDGES;

    // ---- workspace carve-up (256B aligned) ----
    char* ws = (char*)d_ws;
    size_t o = 0;
    auto alloc = [&](size_t bytes) -> void* {
        o = (o + 255) & ~(size_t)255;
        void* p = ws + o;
        o += bytes;
        return p;
    };
    _Float16* A   = (_Float16*)alloc((size_t)N_NODES * HDIM * 2);
    _Float16* C   = (_Float16*)alloc((size_t)N_NODES * HDIM * 2);
    _Float16* h   = (_Float16*)alloc((size_t)N_NODES * HDIM * 2);
    float* Wcat1  = (float*)alloc((size_t)F_IN * 256 * 4);
    _Float16* Wf2 = (_Float16*)alloc((size_t)2 * 16384 * 2);
    _Float16* Wf3 = (_Float16*)alloc((size_t)2 * 16384 * 2);
    // ---- zeroed region: deg .. cnt (single memset) ----
    unsigned* deg  = (unsigned*)alloc((size_t)N_NODES * 4);
    unsigned* bsum = (unsigned*)alloc((size_t)NBLK * 4);
    float* sums    = (float*)alloc((size_t)3 * SUMS_PER_LAYER * 4);
    unsigned* cnt  = (unsigned*)alloc((size_t)16 * 4);   // tickets/done counters
    // ---- not zeroed (fully overwritten before read) ----
    unsigned* off  = (unsigned*)alloc((size_t)N_NODES * 4);
    unsigned* rank = (unsigned*)alloc((size_t)N_EDGES * 4);
    unsigned* ssrc = (unsigned*)alloc((size_t)N_EDGES * 4);
    float* Pp      = (float*)alloc((size_t)POOL_BLKS * HDIM * 4);
    (void)ws_size; (void)n_in; (void)in_sizes; (void)out_size;

    float* sums0 = sums;
    float* sums1 = sums + SUMS_PER_LAYER;
    float* sums2 = sums + 2 * SUMS_PER_LAYER;

    size_t zlen = (size_t)((char*)(cnt + 16) - (char*)deg);
    (void)hipMemsetAsync(deg, 0, zlen, stream);                            // 1

    k_pre<<<PREP_BLKS + HIST_BLKS, 256, 0, stream>>>(W1, W2, W3, Wcat1, Wf2, Wf3,
                                                     dstp, deg, rank);     // 2
    k_scansc<<<HIST_BLKS, 256, 0, stream>>>(deg, bsum, off, srcp, dstp, rank,
                                            ssrc, &cnt[7], &cnt[6]);       // 3

    const int AGB = N_NODES / 4;

    // layer 1
    k_mm1<F_IN, F_IN><<<MM_GRID, 256, 0, stream>>>(x, Wcat1, b1, A, C);                 // 4
    k_agg<<<AGB, 256, 0, stream>>>((const h4*)A, (const h4*)C, off, deg, ssrc, (h4*)h); // 5

    // layer 2 (stats0 stolen in-kernel, then MFMA with BN1)
    k_mmf<<<MM_GRID, 256, 0, stream>>>(h, Wf2, b2, sums0, g1, be1, A, C,
                                       &cnt[0], &cnt[1]);                               // 6
    k_agg<<<AGB, 256, 0, stream>>>((const h4*)A, (const h4*)C, off, deg, ssrc, (h4*)h); // 7

    // layer 3 (stats1 stolen in-kernel, then MFMA with BN2)
    k_mmf<<<MM_GRID, 256, 0, stream>>>(h, Wf3, b3, sums1, g2, be2, A, C,
                                       &cnt[2], &cnt[3]);                               // 8
    k_agg<<<AGB, 256, 0, stream>>>((const h4*)A, (const h4*)C, off, deg, ssrc, (h4*)h); // 9

    // pool partials + BN3 stats + per-graph output in one dispatch
    k_poolout<<<POOL_BLKS, 256, 0, stream>>>(h, Pp, sums2, g3, be3, Wl, bl, out,
                                             &cnt[5]);                                  // 10
}

// Round 10
// 352.762 us; speedup vs baseline: 1.5082x; 1.5082x over previous
//
#include <hip/hip_runtime.h>

#define N_NODES 50000
#define N_EDGES 800000
#define F_IN 24
#define HDIM 128
#define N_GRAPHS 100
#define BN_EPS 1e-5f
#define NBLK 196                          // ceil(N_NODES/256)
#define ROWS_PER_GRAPH (N_NODES / N_GRAPHS)
#define MM_GRID 782                       // ceil(N_NODES/64), 64-row tiles
#define HIST_BLKS ((N_EDGES + 255) / 256) // 3125
#define PREP_BLKS (F_IN + 2 * HDIM)       // 280
#define SSTR 32                           // 32 floats = 128 B: one cache line per channel
#define SUMS_PER_LAYER (256 * SSTR)       // 8192 floats = 32 KB
#define STATS_BLKS 392                    // 128 rows/block: 392 atomics per line
#define POOL_CHUNKS 10
#define POOL_BLKS (N_GRAPHS * POOL_CHUNKS)          // 1000 blocks: ~4/CU
#define ROWS_PER_CHUNK (ROWS_PER_GRAPH / POOL_CHUNKS) // 50

// ============================ MEASURED LESSON BANK ============================
// R1: no nontemporal hints — A/h are LLC-reused by the next dispatch (+4us).
// R2: do NOT fuse BN stats into k_agg via per-block atomics (4 rows/block can't
//     amortize -> 3.2-4.8M device atomics -> 283us/agg, WRITE_SIZE 125MB).
// R4: agg is NOT latency-bound (A-hoist / deep-batch / predicated tail ~ -3us).
// R5: do NOT channel-split the gather (sub-128B-line segments + phase eviction
//     grew FETCH 92->133MB; per-batch shfl broadcast made it VALU-bound, 60us).
//     The ~92MB/agg FETCH == 8 XCDs x unique-rows x 256B compulsory refetch at
//     LLC random-gather BW (~2.5 TB/s) — a structural floor.
// R6: fp16 A halved A traffic (-12us), absmax unchanged (sum already fp16-
//     rounded at h). BEST MEASURED CONFIG = this file (353.8us).
// R7: block-role fusion needs matched resource footprints (scatter inherited
//     mm1's 208 VGPR + 31KB LDS -> occupancy collapse, 44.7us fused dispatch).
// R8: h4 2-rows-per-instruction agg = neutral (355.4) — issue-rate not the
//     limit either; third confirmation of the R5 fabric-floor model.
// R9: in-kernel poll-barriers (ticket steal + atomicAdd(p,0) spin) are
//     CATASTROPHIC at large grids: 3125 blocks spinning RMWs on one line
//     serialize the LLC slice -> k_scansc 110-122us (vs ~15-20 split), total
//     532us. Launch gaps are NOT capturable by software barriers here.
// =============================================================================

typedef _Float16 h2 __attribute__((ext_vector_type(2)));   // packed fp16 pair
typedef _Float16 h4 __attribute__((ext_vector_type(4)));   // 4 fp16 = 8 B
typedef _Float16 f16x8 __attribute__((ext_vector_type(8))); // MFMA A/B frag (4 VGPR)
typedef float f32x4 __attribute__((ext_vector_type(4)));    // MFMA C/D frag

// ---------------- layer-1 matmul (vector, K=24), BOTH planes in one block --------
// A(fp16) = X@(Wt-Wb)+b ; C(fp16) = X@Wb. Merged planes: X staged once.
template <int K, int KC>
__global__ __launch_bounds__(256) void k_mm1(const float* __restrict__ X,
                                             const float* __restrict__ Wcat,
                                             const float* __restrict__ bias,
                                             _Float16* __restrict__ A, _Float16* __restrict__ C) {
    __shared__ float Xs[KC * 68];    // [kk][row], pad 64->68
    __shared__ float Ws[KC * 256];   // [kk][col] both planes
    int tid = threadIdx.x;
    int row0 = blockIdx.x * 64;
    int cg = tid & 31;
    int rg = tid >> 5;

    float accA[8][4], accC[8][4];
#pragma unroll
    for (int ri = 0; ri < 8; ++ri)
#pragma unroll
        for (int ci = 0; ci < 4; ++ci) {
            accA[ri][ci] = bias[cg * 4 + ci];
            accC[ri][ci] = 0.f;
        }

    for (int k0 = 0; k0 < K; k0 += KC) {
        __syncthreads();
        {
            const int C4 = KC / 4;
            for (int i = tid; i < 64 * C4; i += 256) {
                int c4 = i % C4, r = i / C4;
                int row = row0 + r;
                float4 v = make_float4(0.f, 0.f, 0.f, 0.f);
                if (row < N_NODES) v = *(const float4*)&X[row * K + k0 + c4 * 4];
                Xs[(c4 * 4 + 0) * 68 + r] = v.x;
                Xs[(c4 * 4 + 1) * 68 + r] = v.y;
                Xs[(c4 * 4 + 2) * 68 + r] = v.z;
                Xs[(c4 * 4 + 3) * 68 + r] = v.w;
            }
        }
        for (int i = tid; i < KC * 64; i += 256) {
            int c4 = i & 63, kr = i >> 6;
            *(float4*)&Ws[kr * 256 + c4 * 4] =
                *(const float4*)&Wcat[(k0 + kr) * 256 + c4 * 4];
        }
        __syncthreads();
#pragma unroll
        for (int kk = 0; kk < KC; ++kk) {
            float4 t0 = *(const float4*)&Xs[kk * 68 + rg * 8];
            float4 t1 = *(const float4*)&Xs[kk * 68 + rg * 8 + 4];
            float4 wa = *(const float4*)&Ws[kk * 256 + cg * 4];
            float4 wc = *(const float4*)&Ws[kk * 256 + 128 + cg * 4];
            float t[8] = {t0.x, t0.y, t0.z, t0.w, t1.x, t1.y, t1.z, t1.w};
            float wav[4] = {wa.x, wa.y, wa.z, wa.w};
            float wcv[4] = {wc.x, wc.y, wc.z, wc.w};
#pragma unroll
            for (int ri = 0; ri < 8; ++ri)
#pragma unroll
                for (int ci = 0; ci < 4; ++ci) {
                    accA[ri][ci] += t[ri] * wav[ci];
                    accC[ri][ci] += t[ri] * wcv[ci];
                }
        }
    }

#pragma unroll
    for (int ri = 0; ri < 8; ++ri) {
        int row = row0 + rg * 8 + ri;
        if (row < N_NODES) {
            union { h2 h[2]; uint2 u; } pa;
            pa.h[0] = h2{(_Float16)accA[ri][0], (_Float16)accA[ri][1]};
            pa.h[1] = h2{(_Float16)accA[ri][2], (_Float16)accA[ri][3]};
            *(uint2*)&A[row * HDIM + cg * 4] = pa.u;
            union { h2 h[2]; uint2 u; } pk;
            pk.h[0] = h2{(_Float16)accC[ri][0], (_Float16)accC[ri][1]};
            pk.h[1] = h2{(_Float16)accC[ri][2], (_Float16)accC[ri][3]};
            *(uint2*)&C[row * HDIM + cg * 4] = pk.u;
        }
    }
}

// ---------------- layers 2/3: MFMA matmul, BOTH planes in one block --------------
// h read + BN + Xh staging done ONCE; Wh reloaded between planes. A stored fp16.
// BN scale/shift derived in-block from previous dispatch's sums (plain loads;
// kernel-boundary acquire gives cross-XCD visibility — NO in-kernel device fence).
__global__ __launch_bounds__(256) void k_mmf(const _Float16* __restrict__ X,   // h, fp16
                                             const _Float16* __restrict__ Wf, // 2 planes x 16384, frag-linear
                                             const float* __restrict__ bias,
                                             const float* __restrict__ sums,  // padded stats
                                             const float* __restrict__ g,
                                             const float* __restrict__ be,
                                             _Float16* __restrict__ A, _Float16* __restrict__ C) {
    __shared__ _Float16 Xh[16 * 520];      // 16 frags x 1040 B
    __shared__ _Float16 Wh[128 * 128];     // 32 KB, reloaded per plane
    __shared__ float scs[128], shs[128];
    int tid = threadIdx.x;
    int lane = tid & 63, wv = tid >> 6;
    int row0 = blockIdx.x * 64;

    if (tid < 128) {
        float S  = sums[tid * SSTR];
        float S2 = sums[(128 + tid) * SSTR];
        float mean = S / (float)N_NODES;
        float var = fmaxf(S2 / (float)N_NODES - mean * mean, 0.f);
        float scv = g[tid] / sqrtf(var + BN_EPS);
        scs[tid] = scv;
        shs[tid] = be[tid] - mean * scv;
    }
    {
        const uint4* s = (const uint4*)Wf;          // plane 0
        uint4* d = (uint4*)Wh;
        for (int i = tid; i < 2048; i += 256) d[i] = s[i];
    }
    __syncthreads();
    for (int i = tid; i < 64 * 32; i += 256) {
        int k4 = i & 31, rl = i >> 5;
        int row = row0 + rl;
        float4 v = make_float4(0.f, 0.f, 0.f, 0.f);
        if (row < N_NODES) {
            h4 xv = *(const h4*)&X[row * HDIM + k4 * 4];
            v = make_float4((float)xv.x, (float)xv.y, (float)xv.z, (float)xv.w);
        }
        int c = k4 * 4;
        v.x = fmaxf(v.x * scs[c + 0] + shs[c + 0], 0.f);
        v.y = fmaxf(v.y * scs[c + 1] + shs[c + 1], 0.f);
        v.z = fmaxf(v.z * scs[c + 2] + shs[c + 2], 0.f);
        v.w = fmaxf(v.w * scs[c + 3] + shs[c + 3], 0.f);
        int rt = rl >> 4, m = rl & 15, kc = k4 >> 3, q = (k4 >> 1) & 3, jh = k4 & 1;
        _Float16* dp = Xh + (rt * 4 + kc) * 520 + (q * 16 + m) * 8 + jh * 4;
        dp[0] = (_Float16)v.x; dp[1] = (_Float16)v.y;
        dp[2] = (_Float16)v.z; dp[3] = (_Float16)v.w;
    }
    __syncthreads();

    int n = lane & 15, q = lane >> 4;
    f32x4 acc[8];

    // ---- plane 0 -> A (bias init) ----
#pragma unroll
    for (int nt = 0; nt < 8; ++nt) {
        float b0 = bias[nt * 16 + n];
        acc[nt] = f32x4{b0, b0, b0, b0};
    }
#pragma unroll
    for (int kc = 0; kc < 4; ++kc) {
        f16x8 a = *(const f16x8*)(Xh + (wv * 4 + kc) * 520 + lane * 8);
#pragma unroll
        for (int nt = 0; nt < 8; ++nt) {
            f16x8 b = *(const f16x8*)(Wh + ((nt * 4 + kc) * 64 + lane) * 8);
            acc[nt] = __builtin_amdgcn_mfma_f32_16x16x32_f16(a, b, acc[nt], 0, 0, 0);
        }
    }
#pragma unroll
    for (int nt = 0; nt < 8; ++nt) {
#pragma unroll
        for (int r = 0; r < 4; ++r) {
            int row = row0 + wv * 16 + q * 4 + r;
            if (row < N_NODES) A[row * HDIM + nt * 16 + n] = (_Float16)acc[nt][r];
        }
    }
    __syncthreads();                       // all Wh plane-0 reads done
    {
        const uint4* s = (const uint4*)(Wf + 16384);   // plane 1
        uint4* d = (uint4*)Wh;
        for (int i = tid; i < 2048; i += 256) d[i] = s[i];
    }
    __syncthreads();

    // ---- plane 1 -> C (zero init) ----
#pragma unroll
    for (int nt = 0; nt < 8; ++nt) acc[nt] = f32x4{0.f, 0.f, 0.f, 0.f};
#pragma unroll
    for (int kc = 0; kc < 4; ++kc) {
        f16x8 a = *(const f16x8*)(Xh + (wv * 4 + kc) * 520 + lane * 8);
#pragma unroll
        for (int nt = 0; nt < 8; ++nt) {
            f16x8 b = *(const f16x8*)(Wh + ((nt * 4 + kc) * 64 + lane) * 8);
            acc[nt] = __builtin_amdgcn_mfma_f32_16x16x32_f16(a, b, acc[nt], 0, 0, 0);
        }
    }
#pragma unroll
    for (int nt = 0; nt < 8; ++nt) {
#pragma unroll
        for (int r = 0; r < 4; ++r) {
            int row = row0 + wv * 16 + q * 4 + r;
            if (row < N_NODES) C[row * HDIM + nt * 16 + n] = (_Float16)acc[nt][r];
        }
    }
}

// ---------------- fused: weight prep + degree histogram (rank recorded) ----------
__global__ void k_pre(const float* __restrict__ W1, const float* __restrict__ W2,
                      const float* __restrict__ W3, float* __restrict__ Wcat1,
                      _Float16* __restrict__ Wf2, _Float16* __restrict__ Wf3,
                      const int* __restrict__ dst, unsigned* __restrict__ deg,
                      unsigned* __restrict__ rank) {
    int b = blockIdx.x;
    int j = threadIdx.x;
    if (b < F_IN) {
        float wb = W1[(b + F_IN) * HDIM + (j & 127)];
        float wt = W1[b * HDIM + (j & 127)];
        Wcat1[b * 256 + j] = (j < HDIM) ? (wt - wb) : wb;
    } else if (b < PREP_BLKS) {
        int idx = b - F_IN;
        int layer = idx >> 7;
        int k = idx & 127;
        const float* W = layer ? W3 : W2;
        _Float16* Wf   = layer ? Wf3 : Wf2;
        int col = j & 127;
        float wt = W[k * HDIM + col];
        float wb = W[(k + HDIM) * HDIM + col];
        float v = (j < 128) ? (wt - wb) : wb;
        int plane = j >> 7;
        int nt = col >> 4, n = col & 15, kc = k >> 5, q = (k >> 3) & 3, jj = k & 7;
        int f = ((nt * 4 + kc) * 4 + q) * 128 + n * 8 + jj;
        Wf[plane * 16384 + f] = (_Float16)v;
    } else {
        int e = (b - PREP_BLKS) * 256 + j;
        if (e < N_EDGES) rank[e] = atomicAdd(&deg[dst[e]], 1u);
    }
}

// ---------------- single-kernel scan ---------------------------------------------
__global__ __launch_bounds__(256) void k_scanall(const unsigned* __restrict__ deg,
                                                 unsigned* __restrict__ bsum,  // zeroed
                                                 unsigned* __restrict__ off) {
    __shared__ unsigned s[256];
    int t = threadIdx.x;
    int b = blockIdx.x;
    int i = b * 256 + t;
    unsigned v = (i < N_NODES) ? deg[i] : 0u;
    s[t] = v;
    __syncthreads();
    for (int d = 1; d < 256; d <<= 1) {
        unsigned u = (t >= d) ? s[t - d] : 0u;
        __syncthreads();
        s[t] += u;
        __syncthreads();
    }
    unsigned locex = s[t] - v;
    if (t == 255) atomicExch(&bsum[b], s[255] + 1u);
    __syncthreads();
    unsigned bs = 0;
    if (t < NBLK) {
        unsigned x;
        do { x = atomicAdd(&bsum[t], 0u); } while (x == 0u);
        bs = x - 1u;
    }
    s[t] = (t < NBLK) ? bs : 0u;
    __syncthreads();
    for (int d = 1; d < 256; d <<= 1) {
        unsigned u = (t >= d) ? s[t - d] : 0u;
        __syncthreads();
        s[t] += u;
        __syncthreads();
    }
    unsigned bexcl = (b == 0) ? 0u : s[b - 1];
    if (i < N_NODES) off[i] = bexcl + locex;
}

// ---------------- atomic-free scatter (separate: 8 VGPR, full occupancy) ---------
__global__ void k_scatter(const int* __restrict__ src, const int* __restrict__ dst,
                          const unsigned* __restrict__ off, const unsigned* __restrict__ rank,
                          unsigned* __restrict__ ssrc) {
    int e = blockIdx.x * 256 + threadIdx.x;
    if (e < N_EDGES)
        ssrc[off[dst[e]] + rank[e]] = (unsigned)src[e];
}

// ---------------- aggregation: deep-batched gather (A in fp16) -------------------
// A-load hoisted; 16-deep main batch; predicated 8-batch tail (no serial loads).
// Max is idempotent/commutative -> order changes are value-exact. At the fabric
// compulsory-traffic floor (R4/R5/R8) — do not touch internals further.
__global__ __launch_bounds__(256) void k_agg(const h2* __restrict__ A,       // 64 h2/row
                                             const h2* __restrict__ Cc,      // 64 h2/row
                                             const unsigned* __restrict__ off,
                                             const unsigned* __restrict__ deg,
                                             const unsigned* __restrict__ ssrc,
                                             h2* __restrict__ H) {            // 64 h2/row
    __shared__ unsigned sl[4][64];
    int w = threadIdx.x >> 6;
    int lane = threadIdx.x & 63;
    int i = blockIdx.x * 4 + w;
    int d = (int)deg[i];
    unsigned o = off[i];
    h2 a = A[i * 64 + lane];                      // hoisted: overlaps gather
    union { unsigned short us[2]; h2 v; } ninf;
    ninf.us[0] = 0xFC00; ninf.us[1] = 0xFC00;
    const h2 NI = ninf.v;
    h2 m2 = NI;
    for (int base = 0; base < d; base += 64) {
        int cntc = min(64, d - base);
        if (lane < cntc) sl[w][lane] = ssrc[o + base + lane];
        int e = 0;
        for (; e + 16 <= cntc; e += 16) {
            unsigned s[16];
#pragma unroll
            for (int j = 0; j < 16; ++j) s[j] = sl[w][e + j];
            h2 v[16];
#pragma unroll
            for (int j = 0; j < 16; ++j) v[j] = Cc[s[j] * 64 + lane];
#pragma unroll
            for (int st = 8; st > 0; st >>= 1)
#pragma unroll
                for (int j = 0; j < st; ++j)
                    v[j] = __builtin_elementwise_max(v[j], v[j + st]);
            m2 = __builtin_elementwise_max(m2, v[0]);
        }
        if (e + 8 <= cntc) {
            unsigned s[8];
#pragma unroll
            for (int j = 0; j < 8; ++j) s[j] = sl[w][e + j];
            h2 v[8];
#pragma unroll
            for (int j = 0; j < 8; ++j) v[j] = Cc[s[j] * 64 + lane];
#pragma unroll
            for (int st = 4; st > 0; st >>= 1)
#pragma unroll
                for (int j = 0; j < st; ++j)
                    v[j] = __builtin_elementwise_max(v[j], v[j + st]);
            m2 = __builtin_elementwise_max(m2, v[0]);
            e += 8;
        }
        if (e < cntc) {
            int last = cntc - 1;
            unsigned s[8];
#pragma unroll
            for (int j = 0; j < 8; ++j) {
                int idx = e + j;
                s[j] = sl[w][idx < last ? idx : last];
            }
            h2 v[8];
#pragma unroll
            for (int j = 0; j < 8; ++j) v[j] = Cc[s[j] * 64 + lane];
#pragma unroll
            for (int j = 0; j < 8; ++j)
                if (e + j >= cntc) v[j] = NI;
#pragma unroll
            for (int st = 4; st > 0; st >>= 1)
#pragma unroll
                for (int j = 0; j < st; ++j)
                    v[j] = __builtin_elementwise_max(v[j], v[j + st]);
            m2 = __builtin_elementwise_max(m2, v[0]);
        }
    }
    float hx = (d > 0) ? fmaxf((float)a.x + (float)m2.x, 0.f) : 0.f;
    float hy = (d > 0) ? fmaxf((float)a.y + (float)m2.y, 0.f) : 0.f;
    H[i * 64 + lane] = h2{(_Float16)hx, (_Float16)hy};
}

// ---------------- BN stats over fp16 h: 392 blocks, fp32 accumulate --------------
__global__ __launch_bounds__(256) void k_stats(const _Float16* __restrict__ H,
                                               float* __restrict__ sums) {  // zeroed, padded
    __shared__ float4 ls[256], ls2[256];
    int t = threadIdx.x;
    int c4 = t & 31, rg = t >> 5;
    int row0 = blockIdx.x * 128;
    float4 s = make_float4(0.f, 0.f, 0.f, 0.f);
    float4 s2 = make_float4(0.f, 0.f, 0.f, 0.f);
#pragma unroll 4
    for (int it = 0; it < 16; ++it) {
        int row = row0 + rg * 16 + it;
        if (row < N_NODES) {
            h4 hv = *(const h4*)&H[row * HDIM + c4 * 4];
            float4 v = make_float4((float)hv.x, (float)hv.y, (float)hv.z, (float)hv.w);
            s.x += v.x; s.y += v.y; s.z += v.z; s.w += v.w;
            s2.x += v.x * v.x; s2.y += v.y * v.y; s2.z += v.z * v.z; s2.w += v.w * v.w;
        }
    }
    ls[t] = s; ls2[t] = s2;
    __syncthreads();
    if (t < 32) {
        float4 a = ls[t], a2 = ls2[t];
#pragma unroll
        for (int j = 1; j < 8; ++j) {
            float4 b = ls[j * 32 + t], b2 = ls2[j * 32 + t];
            a.x += b.x; a.y += b.y; a.z += b.z; a.w += b.w;
            a2.x += b2.x; a2.y += b2.y; a2.z += b2.z; a2.w += b2.w;
        }
        int c = t * 4;
        atomicAdd(&sums[(c + 0) * SSTR], a.x);
        atomicAdd(&sums[(c + 1) * SSTR], a.y);
        atomicAdd(&sums[(c + 2) * SSTR], a.z);
        atomicAdd(&sums[(c + 3) * SSTR], a.w);
        atomicAdd(&sums[(128 + c + 0) * SSTR], a2.x);
        atomicAdd(&sums[(128 + c + 1) * SSTR], a2.y);
        atomicAdd(&sums[(128 + c + 2) * SSTR], a2.z);
        atomicAdd(&sums[(128 + c + 3) * SSTR], a2.w);
    }
}

// ---------------- pooling: 1000 blocks, vectorized; per-chunk partials + BN3 stats
__global__ __launch_bounds__(256) void k_pool2(const _Float16* __restrict__ H,
                                               float* __restrict__ Pp,     // [1000][128]
                                               float* __restrict__ sums) { // zeroed, padded
    __shared__ float4 ls[256], ls2[256];
    int t = threadIdx.x;
    int c4 = t & 31, rg = t >> 5;
    int b = blockIdx.x;
    int base = (b / POOL_CHUNKS) * ROWS_PER_GRAPH + (b % POOL_CHUNKS) * ROWS_PER_CHUNK;
    float4 s = make_float4(0.f, 0.f, 0.f, 0.f);
    float4 s2 = make_float4(0.f, 0.f, 0.f, 0.f);
#pragma unroll
    for (int j = 0; j < 7; ++j) {
        int rl = rg + j * 8;
        if (rl < ROWS_PER_CHUNK) {
            int row = base + rl;
            h4 hv = *(const h4*)&H[row * HDIM + c4 * 4];
            float4 v = make_float4((float)hv.x, (float)hv.y, (float)hv.z, (float)hv.w);
            s.x += v.x; s.y += v.y; s.z += v.z; s.w += v.w;
            s2.x += v.x * v.x; s2.y += v.y * v.y; s2.z += v.z * v.z; s2.w += v.w * v.w;
        }
    }
    ls[t] = s; ls2[t] = s2;
    __syncthreads();
    if (t < 32) {
        float4 a = ls[t], a2 = ls2[t];
#pragma unroll
        for (int j = 1; j < 8; ++j) {
            float4 q = ls[j * 32 + t], q2 = ls2[j * 32 + t];
            a.x += q.x; a.y += q.y; a.z += q.z; a.w += q.w;
            a2.x += q2.x; a2.y += q2.y; a2.z += q2.z; a2.w += q2.w;
        }
        int c = t * 4;
        *(float4*)&Pp[b * HDIM + c] = a;       // exact per-chunk partial, no atomic
        atomicAdd(&sums[(c + 0) * SSTR], a.x);
        atomicAdd(&sums[(c + 1) * SSTR], a.y);
        atomicAdd(&sums[(c + 2) * SSTR], a.z);
        atomicAdd(&sums[(c + 3) * SSTR], a.w);
        atomicAdd(&sums[(128 + c + 0) * SSTR], a2.x);
        atomicAdd(&sums[(128 + c + 1) * SSTR], a2.y);
        atomicAdd(&sums[(128 + c + 2) * SSTR], a2.z);
        atomicAdd(&sums[(128 + c + 3) * SSTR], a2.w);
    }
}

// ---------------- final: BN3 (from sums) + linear + relu, 1 block/graph ----------
__global__ __launch_bounds__(128) void k_out(const float* __restrict__ Pp,
                                             const float* __restrict__ sums,
                                             const float* __restrict__ g3,
                                             const float* __restrict__ be3,
                                             const float* __restrict__ Wl,
                                             const float* __restrict__ bl,
                                             float* __restrict__ out) {
    int g = blockIdx.x;
    int k = threadIdx.x;
    float S  = sums[k * SSTR];
    float S2 = sums[(128 + k) * SSTR];
    float mean = S / (float)N_NODES;
    float var = fmaxf(S2 / (float)N_NODES - mean * mean, 0.f);
    float scv = g3[k] / sqrtf(var + BN_EPS);
    float shv = be3[k] - mean * scv;
    float pooled = 0.f;
#pragma unroll
    for (int j = 0; j < POOL_CHUNKS; ++j)
        pooled += Pp[(g * POOL_CHUNKS + j) * HDIM + k];
    float p = (scv * (pooled * (1.f / (float)ROWS_PER_GRAPH)) + shv) * Wl[k];
    __shared__ float red[2];
    for (int o = 32; o > 0; o >>= 1) p += __shfl_down(p, o);
    if ((k & 63) == 0) red[k >> 6] = p;
    __syncthreads();
    if (k == 0) out[g] = fmaxf(red[0] + red[1] + bl[0], 0.f);
}

// ---------------- launcher --------------------------------------------------------
extern "C" void kernel_launch(void* const* d_in, const int* in_sizes, int n_in,
                              void* d_out, int out_size, void* d_ws, size_t ws_size,
                              hipStream_t stream) {
    const float* x   = (const float*)d_in[0];
    const int* ei    = (const int*)d_in[1];
    const float* W1  = (const float*)d_in[3];
    const float* b1  = (const float*)d_in[4];
    const float* W2  = (const float*)d_in[5];
    const float* b2  = (const float*)d_in[6];
    const float* W3  = (const float*)d_in[7];
    const float* b3  = (const float*)d_in[8];
    const float* g1  = (const float*)d_in[9];
    const float* be1 = (const float*)d_in[10];
    const float* g2  = (const float*)d_in[11];
    const float* be2 = (const float*)d_in[12];
    const float* g3  = (const float*)d_in[13];
    const float* be3 = (const float*)d_in[14];
    const float* Wl  = (const float*)d_in[15];
    const float* bl  = (const float*)d_in[16];
    float* out = (float*)d_out;

    const int* srcp = ei;
    const int* dstp = ei + N_EDGES;

    // ---- workspace carve-up (256B aligned) ----
    char* ws = (char*)d_ws;
    size_t o = 0;
    auto alloc = [&](size_t bytes) -> void* {
        o = (o + 255) & ~(size_t)255;
        void* p = ws + o;
        o += bytes;
        return p;
    };
    _Float16* A   = (_Float16*)alloc((size_t)N_NODES * HDIM * 2);   // fp16
    _Float16* C   = (_Float16*)alloc((size_t)N_NODES * HDIM * 2);
    _Float16* h   = (_Float16*)alloc((size_t)N_NODES * HDIM * 2);
    float* Wcat1  = (float*)alloc((size_t)F_IN * 256 * 4);
    _Float16* Wf2 = (_Float16*)alloc((size_t)2 * 16384 * 2);
    _Float16* Wf3 = (_Float16*)alloc((size_t)2 * 16384 * 2);
    // ---- zeroed region: deg .. sums (single memset) ----
    unsigned* deg  = (unsigned*)alloc((size_t)N_NODES * 4);
    unsigned* bsum = (unsigned*)alloc((size_t)NBLK * 4);
    float* sums    = (float*)alloc((size_t)3 * SUMS_PER_LAYER * 4);  // 96 KB padded
    // ---- not zeroed (fully overwritten before read) ----
    unsigned* off  = (unsigned*)alloc((size_t)N_NODES * 4);
    unsigned* rank = (unsigned*)alloc((size_t)N_EDGES * 4);
    unsigned* ssrc = (unsigned*)alloc((size_t)N_EDGES * 4);
    float* Pp      = (float*)alloc((size_t)POOL_BLKS * HDIM * 4);    // 512 KB partials
    (void)ws_size; (void)n_in; (void)in_sizes; (void)out_size;

    float* sums0 = sums;
    float* sums1 = sums + SUMS_PER_LAYER;
    float* sums2 = sums + 2 * SUMS_PER_LAYER;

    size_t zlen = (size_t)((char*)(sums + 3 * SUMS_PER_LAYER) - (char*)deg);
    (void)hipMemsetAsync(deg, 0, zlen, stream);                        // 1

    k_pre<<<PREP_BLKS + HIST_BLKS, 256, 0, stream>>>(W1, W2, W3, Wcat1, Wf2, Wf3,
                                                     dstp, deg, rank); // 2
    k_scanall<<<NBLK, 256, 0, stream>>>(deg, bsum, off);               // 3
    k_scatter<<<HIST_BLKS, 256, 0, stream>>>(srcp, dstp, off, rank, ssrc); // 4

    const int AGB = N_NODES / 4;

    // layer 1
    k_mm1<F_IN, F_IN><<<MM_GRID, 256, 0, stream>>>(x, Wcat1, b1, A, C);             // 5
    k_agg<<<AGB, 256, 0, stream>>>((const h2*)A, (const h2*)C, off, deg, ssrc, (h2*)h); // 6
    k_stats<<<STATS_BLKS, 256, 0, stream>>>(h, sums0);                              // 7

    // layer 2 (MFMA, BN1 derived in-block from sums0)
    k_mmf<<<MM_GRID, 256, 0, stream>>>(h, Wf2, b2, sums0, g1, be1, A, C);           // 8
    k_agg<<<AGB, 256, 0, stream>>>((const h2*)A, (const h2*)C, off, deg, ssrc, (h2*)h); // 9
    k_stats<<<STATS_BLKS, 256, 0, stream>>>(h, sums1);                              // 10

    // layer 3 (MFMA, BN2 derived in-block from sums1)
    k_mmf<<<MM_GRID, 256, 0, stream>>>(h, Wf3, b3, sums1, g2, be2, A, C);           // 11
    k_agg<<<AGB, 256, 0, stream>>>((const h2*)A, (const h2*)C, off, deg, ssrc, (h2*)h); // 12

    // chunked pool partials + layer-3 stats in one h pass, then per-graph output
    k_pool2<<<POOL_BLKS, 256, 0, stream>>>(h, Pp, sums2);                           // 13
    k_out<<<N_GRAPHS, 128, 0, stream>>>(Pp, sums2, g3, be3, Wl, bl, out);           // 14
}